// Round 11
// baseline (57.063 us; speedup 1.0000x reference)
//
#include <hip/hip_runtime.h>

#define B_ 256
#define M_ 512
#define N_ 256
#define K_ 16
#define TROWS 256            // rows per block tile
#define NC 16                // n-cols per chunk
#define NPHASE (N_ / NC)     // 16

// direct global->LDS, 16B per lane, no VGPR staging
__device__ __forceinline__ void gload_lds16(const float* g, float* l) {
    __builtin_amdgcn_global_load_lds(
        (const __attribute__((address_space(1))) void*)g,
        (__attribute__((address_space(3))) void*)l,
        16, 0, 0);
}

// ---------------- Pass 1 ----------------
// R7/R10 geometry/mapping (proven conflict-free, clean traffic) + TRIPLE
// buffer, 2-phase-ahead prefetch: iteration p issues phase p+2's loads,
// waits vmcnt(8) (phase p landed; p+1/p+2 in flight across the barrier).
// grid = B_*2 = 512 blocks (2/CU, LDS 65.6KB -> cap 2/CU, exact fit).
// Thread t = (rs = t>>2 in 0..63, ksub = t&3): owns rows {rs, rs+64,
// rs+128, rs+192}, k-quad [ksub*4, +4). x-reads 16-row/wave 4-lane-broadcast.
__global__ __launch_bounds__(256) void fm_pass1(
    const float* __restrict__ x, const float* __restrict__ w,
    const float* __restrict__ bias, const float* __restrict__ v,
    float* __restrict__ xv, float* __restrict__ svpart, float* __restrict__ out)
{
    __shared__ __align__(16) float vL[N_][K_];                   // 16 KiB
    __shared__ __align__(16) float wL[N_];                       // 1 KiB
    __shared__ __align__(16) unsigned char xT[3][TROWS * NC * 4];// 3 x 16 KiB
    __shared__ __align__(16) float red[64];                      // sv partials

    const int t    = threadIdx.x;
    const int rs   = t >> 2;        // 0..63
    const int ksub = t & 3;
    const int blk  = blockIdx.x;
    const int b    = blk >> 1;
    const int m0   = (blk & 1) * TROWS;

    // stage v (4096 floats) and w (256 floats) once
    {
        const float4* v4 = (const float4*)v;
        float4* vL4 = (float4*)&vL[0][0];
        #pragma unroll
        for (int i = 0; i < 4; ++i) vL4[t + 256 * i] = v4[t + 256 * i];
        wL[t] = w[t];
    }

    const float* xb = x + ((size_t)b * M_ + m0) * N_;

    // staging (R7 exact): round i covers rows 64i..64i+63, 64 B per row.
    // LDS dest linear (wave base + lane*16); source col-quad pre-swizzled with
    // the same XOR used on the read side.
    const int srow = t >> 2;                       // 0..63
    const int sq   = (t & 3) ^ ((srow >> 1) & 3);  // swizzled source col-quad
    const int wofs = (t & 192) * 16;               // wave-uniform segment base

    float4 a0 = {0,0,0,0}, a1 = {0,0,0,0}, a2 = {0,0,0,0}, a3 = {0,0,0,0};
    float l0 = 0.f, l1 = 0.f, l2 = 0.f, l3 = 0.f;  // linear term (ksub==0)

    const int qx = (rs >> 1) & 3;
    const float bias0 = bias[0];

    // prologue: phases 0 and 1 -> buf 0, buf 1 (4 loads/thread each)
    #pragma unroll
    for (int i = 0; i < 4; ++i)
        gload_lds16(xb + (size_t)(srow + 64 * i) * N_ + 0 * NC + sq * 4,
                    (float*)(xT[0] + i * 4096 + wofs));
    #pragma unroll
    for (int i = 0; i < 4; ++i)
        gload_lds16(xb + (size_t)(srow + 64 * i) * N_ + 1 * NC + sq * 4,
                    (float*)(xT[1] + i * 4096 + wofs));
    asm volatile("s_waitcnt lgkmcnt(0)" ::: "memory");   // v/w ds_writes done

    for (int p = 0; p < NPHASE; ++p) {
        // issue phase p+2 (stays in flight across the barrier, 2-deep)
        if (p + 2 < NPHASE) {
            const float* src = xb + (p + 2) * NC + sq * 4;
            unsigned char* dst = xT[(p + 2) % 3];
            #pragma unroll
            for (int i = 0; i < 4; ++i)
                gload_lds16(src + (size_t)(srow + 64 * i) * N_,
                            (float*)(dst + i * 4096 + wofs));
            asm volatile("s_waitcnt vmcnt(8)" ::: "memory");  // p landed
        } else if (p + 1 < NPHASE) {
            asm volatile("s_waitcnt vmcnt(4)" ::: "memory");  // p landed
        } else {
            asm volatile("s_waitcnt vmcnt(0)" ::: "memory");
        }
        __builtin_amdgcn_s_barrier();           // tile p visible block-wide
        asm volatile("" ::: "memory");

        const unsigned char* const xr = xT[p % 3] + rs * 64;
        #pragma unroll
        for (int q = 0; q < NC / 4; ++q) {
            const int qoff = ((q ^ qx) << 4);
            const float4 x0 = *(const float4*)(xr +         qoff);
            const float4 x1 = *(const float4*)(xr +  4096 + qoff);
            const float4 x2 = *(const float4*)(xr +  8192 + qoff);
            const float4 x3 = *(const float4*)(xr + 12288 + qoff);
            const int n0 = p * NC + q * 4;
            const float4 v0 = *(const float4*)&vL[n0 + 0][ksub * 4];
            const float4 v1 = *(const float4*)&vL[n0 + 1][ksub * 4];
            const float4 v2 = *(const float4*)&vL[n0 + 2][ksub * 4];
            const float4 v3 = *(const float4*)&vL[n0 + 3][ksub * 4];

            a0.x += x0.x*v0.x + x0.y*v1.x + x0.z*v2.x + x0.w*v3.x;
            a0.y += x0.x*v0.y + x0.y*v1.y + x0.z*v2.y + x0.w*v3.y;
            a0.z += x0.x*v0.z + x0.y*v1.z + x0.z*v2.z + x0.w*v3.z;
            a0.w += x0.x*v0.w + x0.y*v1.w + x0.z*v2.w + x0.w*v3.w;

            a1.x += x1.x*v0.x + x1.y*v1.x + x1.z*v2.x + x1.w*v3.x;
            a1.y += x1.x*v0.y + x1.y*v1.y + x1.z*v2.y + x1.w*v3.y;
            a1.z += x1.x*v0.z + x1.y*v1.z + x1.z*v2.z + x1.w*v3.z;
            a1.w += x1.x*v0.w + x1.y*v1.w + x1.z*v2.w + x1.w*v3.w;

            a2.x += x2.x*v0.x + x2.y*v1.x + x2.z*v2.x + x2.w*v3.x;
            a2.y += x2.x*v0.y + x2.y*v1.y + x2.z*v2.y + x2.w*v3.y;
            a2.z += x2.x*v0.z + x2.y*v1.z + x2.z*v2.z + x2.w*v3.z;
            a2.w += x2.x*v0.w + x2.y*v1.w + x2.z*v2.w + x2.w*v3.w;

            a3.x += x3.x*v0.x + x3.y*v1.x + x3.z*v2.x + x3.w*v3.x;
            a3.y += x3.x*v0.y + x3.y*v1.y + x3.z*v2.y + x3.w*v3.y;
            a3.z += x3.x*v0.z + x3.y*v1.z + x3.z*v2.z + x3.w*v3.z;
            a3.w += x3.x*v0.w + x3.y*v1.w + x3.z*v2.w + x3.w*v3.w;

            if (ksub == 0) {
                const float4 wq = *(const float4*)&wL[n0];
                l0 += x0.x*wq.x + x0.y*wq.y + x0.z*wq.z + x0.w*wq.w;
                l1 += x1.x*wq.x + x1.y*wq.y + x1.z*wq.z + x1.w*wq.w;
                l2 += x2.x*wq.x + x2.y*wq.y + x2.z*wq.z + x2.w*wq.w;
                l3 += x3.x*wq.x + x3.y*wq.y + x3.z*wq.z + x3.w*wq.w;
            }
        }
        asm volatile("" ::: "memory");
        __builtin_amdgcn_s_barrier();   // reads of buf p done; overwrite ok
        asm volatile("" ::: "memory");
    }

    // xv writes: 4 rows x float4, coalesced (1 KB contiguous per wave per row-set)
    {
        float* base = xv + ((size_t)b * M_ + m0 + rs) * K_ + ksub * 4;
        *(float4*)(base +   0 * K_) = a0;
        *(float4*)(base +  64 * K_) = a1;
        *(float4*)(base + 128 * K_) = a2;
        *(float4*)(base + 192 * K_) = a3;
    }
    if (ksub == 0) {
        float* ob = out + (size_t)b * M_ + m0 + rs;
        ob[0]   = l0 + bias0;
        ob[64]  = l1 + bias0;
        ob[128] = l2 + bias0;
        ob[192] = l3 + bias0;
    }

    // sv: local 4-row sum, butterfly over rs bits (4,8,16,32), cross-wave via LDS
    float4 s = {a0.x + a1.x + a2.x + a3.x,
                a0.y + a1.y + a2.y + a3.y,
                a0.z + a1.z + a2.z + a3.z,
                a0.w + a1.w + a2.w + a3.w};
    #pragma unroll
    for (int off = 4; off < 64; off <<= 1) {
        s.x += __shfl_xor(s.x, off);
        s.y += __shfl_xor(s.y, off);
        s.z += __shfl_xor(s.z, off);
        s.w += __shfl_xor(s.w, off);
    }
    const int wave = t >> 6;
    if ((t & 63) < 4)
        *(float4*)(red + wave * 16 + ksub * 4) = s;
    __syncthreads();
    if (t < 16)
        svpart[(size_t)blk * 16 + t] = red[t] + red[16 + t] + red[32 + t] + red[48 + t];
}

// ---------------- Pass 2 ----------------
// grid = B_*2 blocks, 256 threads; thread per row.
__global__ __launch_bounds__(256) void fm_pass2(
    const float* __restrict__ xv, const float* __restrict__ svpart,
    float* __restrict__ out)
{
    const int t = threadIdx.x;
    const int blk = blockIdx.x;
    const int b = blk >> 1;
    const int m = (blk & 1) * 256 + t;
    __shared__ __align__(16) float svL[16];
    if (t < 16)
        svL[t] = svpart[(size_t)(b * 2 + 0) * 16 + t] + svpart[(size_t)(b * 2 + 1) * 16 + t];
    __syncthreads();

    const float4* xvp = (const float4*)(xv + ((size_t)b * M_ + m) * K_);
    float4 a0 = xvp[0], a1 = xvp[1], a2 = xvp[2], a3 = xvp[3];
    const float4* s4 = (const float4*)svL;
    float4 s0 = s4[0], s1 = s4[1], s2 = s4[2], s3 = s4[3];

    float rs = a0.x * s0.x + a0.y * s0.y + a0.z * s0.z + a0.w * s0.w
             + a1.x * s1.x + a1.y * s1.y + a1.z * s1.z + a1.w * s1.w
             + a2.x * s2.x + a2.y * s2.y + a2.z * s2.z + a2.w * s2.w
             + a3.x * s3.x + a3.y * s3.y + a3.z * s3.z + a3.w * s3.w;
    float dg = a0.x * a0.x + a0.y * a0.y + a0.z * a0.z + a0.w * a0.w
             + a1.x * a1.x + a1.y * a1.y + a1.z * a1.z + a1.w * a1.w
             + a2.x * a2.x + a2.y * a2.y + a2.z * a2.z + a2.w * a2.w
             + a3.x * a3.x + a3.y * a3.y + a3.z * a3.z + a3.w * a3.w;

    const size_t o = (size_t)b * M_ + m;
    out[o] = out[o] + 0.5f * (rs - dg);
}

extern "C" void kernel_launch(void* const* d_in, const int* in_sizes, int n_in,
                              void* d_out, int out_size, void* d_ws, size_t ws_size,
                              hipStream_t stream) {
    const float* x    = (const float*)d_in[0];
    const float* w    = (const float*)d_in[1];
    const float* bias = (const float*)d_in[2];
    const float* v    = (const float*)d_in[3];
    float* out = (float*)d_out;

    float* xv     = (float*)d_ws;                 // B*M*K floats = 8 MiB
    float* svpart = xv + (size_t)B_ * M_ * K_;    // 512*16 floats

    fm_pass1<<<dim3(B_ * 2), dim3(256), 0, stream>>>(x, w, bias, v, xv, svpart, out);
    fm_pass2<<<dim3(B_ * 2), dim3(256), 0, stream>>>(xv, svpart, out);
}

// Round 12
// 30.558 us; speedup vs baseline: 1.8674x; 1.8674x over previous
//
#include <hip/hip_runtime.h>

#define B_ 256
#define M_ 512
#define N_ 256
#define K_ 16
#define TR 64                 // rows per LDS tile
#define NT 4                  // tiles per block (256 rows)

typedef __attribute__((ext_vector_type(8))) short short8;
typedef __attribute__((ext_vector_type(4))) float f32x4;

__device__ __forceinline__ unsigned short f2bf(float f) {
    unsigned u = __builtin_bit_cast(unsigned, f);
    u += 0x7FFFu + ((u >> 16) & 1u);       // round-to-nearest-even
    return (unsigned short)(u >> 16);
}
__device__ __forceinline__ float bf2f(unsigned short h) {
    unsigned u = ((unsigned)h) << 16;
    return __builtin_bit_cast(float, u);
}

// ---------------- Pass 1 (MFMA, sequential streaming) ----------------
// grid = B_*2 = 512 blocks (2/CU, LDS ~65KB), 256 threads (4 waves).
// Block owns 256 rows = 4 tiles x 64 rows x 256 cols. Per tile:
//   stage: 16 x wave-contiguous float4 loads (4KB/instr/block, SEQUENTIAL)
//          -> cvt bf16 -> swizzled ds_write ([64][256] bf16, quad ^= row&7)
//   mfma : wave wv owns rows [wv*16,+16): 8 x (A-frag ds_read + 16x16x32 bf16)
//          B-frags (v, bf16) persistent in 32 VGPRs -- zero v traffic in loop
//   linear term: 4 threads/row dot bf16 row with bf16 w from LDS
// xv kept in C-frags; written to global for pass2; sv partial via shuffles.
__global__ __launch_bounds__(256) void fm_pass1(
    const float* __restrict__ x, const float* __restrict__ w,
    const float* __restrict__ bias, const float* __restrict__ v,
    float* __restrict__ xv, float* __restrict__ svpart, float* __restrict__ out)
{
    __shared__ __align__(16) unsigned char xL[2][TR * 512];  // 2 x 32 KiB bf16
    __shared__ __align__(16) unsigned short wLb[N_];         // w bf16
    __shared__ __align__(16) float red[64];

    const int t   = threadIdx.x;
    const int l   = t & 63;
    const int wv  = t >> 6;
    const int blk = blockIdx.x;
    const int b   = blk >> 1;
    const int m0  = (blk & 1) * (NT * TR);
    const float bias0 = bias[0];

    // stage w as bf16
    if (t < 64) {
        float4 wq = *(const float4*)(w + t * 4);
        wLb[t * 4 + 0] = f2bf(wq.x); wLb[t * 4 + 1] = f2bf(wq.y);
        wLb[t * 4 + 2] = f2bf(wq.z); wLb[t * 4 + 3] = f2bf(wq.w);
    }

    // B-fragments: v -> bf16, 8 n-chunks, persistent in registers.
    // 16x16x32 bf16 layout: B[k][col]: col = l&15, k = (l>>4)*8 + j.
    short8 vB[8];
    #pragma unroll
    for (int c = 0; c < 8; ++c) {
        #pragma unroll
        for (int j = 0; j < 8; ++j) {
            float f = v[(size_t)(c * 32 + (l >> 4) * 8 + j) * K_ + (l & 15)];
            vB[c][j] = (short)f2bf(f);
        }
    }

    const float* gx = x + (size_t)(b * M_ + m0) * N_;

    // staging geometry: load j covers rows [j*4, j*4+4), wave wv -> row j*4+wv,
    // lane l -> floats [l*4, l*4+4) of that row. 1 KB contiguous per wave-instr.
    const int swq = l >> 1;          // 16B-quad index within row (bf16)
    const int shf = (l & 1) * 8;     // byte within quad

    float4 st[16];
    // prologue: tile 0 -> regs -> bf16 -> buf 0
    #pragma unroll
    for (int j = 0; j < 16; ++j)
        st[j] = *(const float4*)(gx + j * 1024 + t * 4);
    #pragma unroll
    for (int j = 0; j < 16; ++j) {
        const int row = j * 4 + wv;
        unsigned lo = (unsigned)f2bf(st[j].x) | ((unsigned)f2bf(st[j].y) << 16);
        unsigned hi = (unsigned)f2bf(st[j].z) | ((unsigned)f2bf(st[j].w) << 16);
        unsigned* d = (unsigned*)(xL[0] + row * 512 + ((swq ^ (row & 7)) << 4) + shf);
        d[0] = lo; d[1] = hi;
    }
    __syncthreads();

    f32x4 acc[NT];
    #pragma unroll
    for (int T = 0; T < NT; ++T) acc[T] = f32x4{0.f, 0.f, 0.f, 0.f};

    #pragma unroll
    for (int T = 0; T < NT; ++T) {
        const int cur = T & 1;
        // issue next tile's global loads (consumed after MFMA -> latency hidden)
        if (T + 1 < NT) {
            #pragma unroll
            for (int j = 0; j < 16; ++j)
                st[j] = *(const float4*)(gx + (size_t)(T + 1) * TR * N_ + j * 1024 + t * 4);
        }

        // MFMA: wave wv, rows [wv*16, +16). A[row][k]: row = l&15, k = (l>>4)*8+j.
        const int arow = wv * 16 + (l & 15);
        const unsigned char* abase = xL[cur] + arow * 512;
        #pragma unroll
        for (int c = 0; c < 8; ++c) {
            short8 a = *(const short8*)(abase + (((c * 4 + (l >> 4)) ^ (arow & 7)) << 4));
            acc[T] = __builtin_amdgcn_mfma_f32_16x16x32_bf16(a, vB[c], acc[T], 0, 0, 0);
        }

        // linear term for this tile: 4 threads per row, 64-col quarters
        {
            const int row = t >> 2;
            const int qt  = t & 3;
            const unsigned char* rbase = xL[cur] + row * 512;
            float ls = 0.f;
            #pragma unroll
            for (int i = 0; i < 8; ++i) {
                short8 xs = *(const short8*)(rbase + ((((qt * 8 + i)) ^ (row & 7)) << 4));
                short8 ws = *(const short8*)((const unsigned char*)wLb + qt * 128 + i * 16);
                #pragma unroll
                for (int e = 0; e < 8; ++e)
                    ls += bf2f((unsigned short)xs[e]) * bf2f((unsigned short)ws[e]);
            }
            ls += __shfl_xor(ls, 1);
            ls += __shfl_xor(ls, 2);
            if (qt == 0)
                out[(size_t)b * M_ + m0 + T * TR + row] = ls + bias0;
        }

        // convert + write next tile into the other buffer
        if (T + 1 < NT) {
            #pragma unroll
            for (int j = 0; j < 16; ++j) {
                const int row = j * 4 + wv;
                unsigned lo = (unsigned)f2bf(st[j].x) | ((unsigned)f2bf(st[j].y) << 16);
                unsigned hi = (unsigned)f2bf(st[j].z) | ((unsigned)f2bf(st[j].w) << 16);
                unsigned* d = (unsigned*)(xL[cur ^ 1] + row * 512 + ((swq ^ (row & 7)) << 4) + shf);
                d[0] = lo; d[1] = hi;
            }
        }
        __syncthreads();
    }

    // xv global write. C/D layout: col = l&15, row = (l>>4)*4 + reg.
    #pragma unroll
    for (int T = 0; T < NT; ++T) {
        const int rbase = m0 + T * TR + wv * 16 + (l >> 4) * 4;
        #pragma unroll
        for (int r = 0; r < 4; ++r)
            xv[(size_t)(b * M_ + rbase + r) * K_ + (l & 15)] = acc[T][r];
    }

    // sv partial: sum all rows this lane holds, reduce over l>>4, then waves
    float s = 0.f;
    #pragma unroll
    for (int T = 0; T < NT; ++T)
        s += acc[T][0] + acc[T][1] + acc[T][2] + acc[T][3];
    s += __shfl_xor(s, 16);
    s += __shfl_xor(s, 32);
    if (l < 16) red[wv * 16 + l] = s;
    __syncthreads();
    if (t < 16)
        svpart[(size_t)blk * 16 + t] = red[t] + red[16 + t] + red[32 + t] + red[48 + t];
}

// ---------------- Pass 2 (unchanged champion) ----------------
__global__ __launch_bounds__(256) void fm_pass2(
    const float* __restrict__ xv, const float* __restrict__ svpart,
    float* __restrict__ out)
{
    const int t = threadIdx.x;
    const int blk = blockIdx.x;
    const int b = blk >> 1;
    const int m = (blk & 1) * 256 + t;
    __shared__ __align__(16) float svL[16];
    if (t < 16)
        svL[t] = svpart[(size_t)(b * 2 + 0) * 16 + t] + svpart[(size_t)(b * 2 + 1) * 16 + t];
    __syncthreads();

    const float4* xvp = (const float4*)(xv + ((size_t)b * M_ + m) * K_);
    float4 a0 = xvp[0], a1 = xvp[1], a2 = xvp[2], a3 = xvp[3];
    const float4* s4 = (const float4*)svL;
    float4 s0 = s4[0], s1 = s4[1], s2 = s4[2], s3 = s4[3];

    float rs = a0.x * s0.x + a0.y * s0.y + a0.z * s0.z + a0.w * s0.w
             + a1.x * s1.x + a1.y * s1.y + a1.z * s1.z + a1.w * s1.w
             + a2.x * s2.x + a2.y * s2.y + a2.z * s2.z + a2.w * s2.w
             + a3.x * s3.x + a3.y * s3.y + a3.z * s3.z + a3.w * s3.w;
    float dg = a0.x * a0.x + a0.y * a0.y + a0.z * a0.z + a0.w * a0.w
             + a1.x * a1.x + a1.y * a1.y + a1.z * a1.z + a1.w * a1.w
             + a2.x * a2.x + a2.y * a2.y + a2.z * a2.z + a2.w * a2.w
             + a3.x * a3.x + a3.y * a3.y + a3.z * a3.z + a3.w * a3.w;

    const size_t o = (size_t)b * M_ + m;
    out[o] = out[o] + 0.5f * (rs - dg);
}

extern "C" void kernel_launch(void* const* d_in, const int* in_sizes, int n_in,
                              void* d_out, int out_size, void* d_ws, size_t ws_size,
                              hipStream_t stream) {
    const float* x    = (const float*)d_in[0];
    const float* w    = (const float*)d_in[1];
    const float* bias = (const float*)d_in[2];
    const float* v    = (const float*)d_in[3];
    float* out = (float*)d_out;

    float* xv     = (float*)d_ws;                 // B*M*K floats = 8 MiB
    float* svpart = xv + (size_t)B_ * M_ * K_;    // 512*16 floats

    fm_pass1<<<dim3(B_ * 2), dim3(256), 0, stream>>>(x, w, bias, v, xv, svpart, out);
    fm_pass2<<<dim3(B_ * 2), dim3(256), 0, stream>>>(xv, svpart, out);
}